// Round 2
// baseline (957.723 us; speedup 1.0000x reference)
//
#include <hip/hip_runtime.h>

// ResidualConvLSTM2D on MI355X (gfx950).
// Fused per-timestep implicit GEMM: z = conv3x3([x_t || h_{t-1}], [Wx || Wh]) via
// bf16 MFMA (16x16x32), fp32 LSTM cell, fp32 residual 1x1 conv.
//
// ws layout (total 4.50 MB — kept small; a larger footprint overran ws_size and
// corrupted neighboring allocations => deterministic post-timing divergence):
//   [0, 442368)        WcombT bf16 [256][864]
//   [524288, +2MB)     h ping  bf16 [4][64][64][64]
//   [2621440, +2MB)    h pong  bf16
// Cell state c (fp32) lives inside d_out: c_t is stored at out[b][t][y][x][f]
// (read by the same thread that later writes the output there), c_{t+1} goes to
// slab t+1 (overwritten by step t+1's own output after it reads it).
#define B_ 4
#define T_ 16
#define H_ 64
#define W_ 64
#define CIN 32
#define F_ 64
#define NCH 256
#define KTOT 864
#define KSTEPS 27
#define TSLAB (H_ * W_ * F_)   // 262144 floats between (b,t) and (b,t+1)

#define OFF_H0 524288
#define OFF_H1 2621440

typedef __attribute__((ext_vector_type(8))) short short8;
typedef __attribute__((ext_vector_type(4))) float floatx4;

__device__ __forceinline__ unsigned short f2bf(float f) {
  union { float f; unsigned u; } v; v.f = f;
  unsigned r = v.u + 0x7FFFu + ((v.u >> 16) & 1u);   // round-to-nearest-even
  return (unsigned short)(r >> 16);
}

// Build WcombT[n][k] bf16: k = (dy*3+dx)*96 + c; c<32 -> Wx, else Wh.
__global__ void prep_weights(const float* __restrict__ Wx, const float* __restrict__ Wh,
                             unsigned short* __restrict__ WcombT) {
  int idx = blockIdx.x * 256 + threadIdx.x;            // 0..221183
  int n = idx / KTOT;
  int k = idx - n * KTOT;
  int g = k / 96;
  int c = k - g * 96;
  float v = (c < CIN) ? Wx[(g * CIN + c) * NCH + n]
                      : Wh[(g * F_ + (c - CIN)) * NCH + n];
  WcombT[n * KTOT + k] = f2bf(v);
}

// Zero h ping+pong (4 MB in ws): 1024 blocks x 256 threads x 16 B.
__global__ void prep_zero_h(float4* __restrict__ p) {
  int idx = blockIdx.x * 256 + threadIdx.x;
  p[idx] = make_float4(0.f, 0.f, 0.f, 0.f);
}

// Zero c0 = out slabs [b][0][...]: 4 x 262144 floats (non-contiguous per batch).
__global__ void prep_zero_c(float* __restrict__ out) {
  int idx = blockIdx.x * 256 + threadIdx.x;            // 0 .. 262143 (float4 units)
  int b = idx >> 16;                                   // 65536 float4 per batch slab
  int i = idx & 65535;
  ((float4*)(out + (size_t)b * (T_ * TSLAB)))[i] = make_float4(0.f, 0.f, 0.f, 0.f);
}

__global__ __launch_bounds__(256, 1)
void step_kernel(const float* __restrict__ x, const float* __restrict__ bias,
                 const float* __restrict__ Wp, const float* __restrict__ bp,
                 const unsigned short* __restrict__ WcombT,
                 const unsigned short* __restrict__ hprev,
                 unsigned short* __restrict__ hnew,
                 float* __restrict__ out, int t)
{
  // LDS: patch [4][34][104] shorts (28288 B) | bl [256][40] shorts (20480 B)
  // epilogue reuse: gact [4][64][33] floats (33792 B) at 0, WpL 8 KB at 36480
  __shared__ __align__(16) char smem[48768];
  short* patch = (short*)smem;
  short* bl    = (short*)(smem + 28288);
  float* gact  = (float*)smem;
  float* WpL   = (float*)(smem + 36480);

  const int tid  = threadIdx.x;
  const int w    = tid >> 6;
  const int lane = tid & 63;
  const int quad = lane >> 4;
  const int lr   = lane & 15;

  const int bid = blockIdx.x;
  const int b   = bid >> 6;
  const int rem = bid & 63;
  const int y0  = (rem >> 1) << 1;   // 2-row tile
  const int x0  = (rem & 1) << 5;    // 32-col half

  // ---- stage input patch: 4 rows x 34 cols x 96 ch (x bf16 | h bf16)
  if (tid < 136) {
    int sy = tid / 34, sx = tid - sy * 34;
    int yy = y0 + sy - 1, xx = x0 + sx - 1;
    short* dst = patch + tid * 104;
    if (yy >= 0 && yy < H_ && xx >= 0 && xx < W_) {
      const float4* xs = (const float4*)(x + ((((b * T_ + t) * H_ + yy) * W_ + xx) * CIN));
      #pragma unroll
      for (int j = 0; j < 4; j++) {
        float4 f0 = xs[2 * j];
        float4 f1 = xs[2 * j + 1];
        union { short8 v; unsigned short u[8]; } pk;
        pk.u[0] = f2bf(f0.x); pk.u[1] = f2bf(f0.y); pk.u[2] = f2bf(f0.z); pk.u[3] = f2bf(f0.w);
        pk.u[4] = f2bf(f1.x); pk.u[5] = f2bf(f1.y); pk.u[6] = f2bf(f1.z); pk.u[7] = f2bf(f1.w);
        ((short8*)dst)[j] = pk.v;
      }
      const uint4* hs = (const uint4*)(hprev + ((b * H_ + yy) * W_ + xx) * F_);
      uint4* d2 = (uint4*)(dst + 32);
      #pragma unroll
      for (int j = 0; j < 8; j++) d2[j] = hs[j];
    } else {
      uint4 z = make_uint4(0, 0, 0, 0);
      uint4* d4 = (uint4*)dst;
      #pragma unroll
      for (int j = 0; j < 12; j++) d4[j] = z;
    }
  }

  float bias_r[4];
  #pragma unroll
  for (int nf = 0; nf < 4; nf++) bias_r[nf] = bias[w * 64 + nf * 16 + lr];

  floatx4 acc[4][4];
  #pragma unroll
  for (int mf = 0; mf < 4; mf++)
    #pragma unroll
    for (int nf = 0; nf < 4; nf++)
      acc[mf][nf] = (floatx4){0.f, 0.f, 0.f, 0.f};

  // ---- K loop: 27 steps of BK=32 over K=864 (never crosses a 96-ch tap group)
  for (int s = 0; s < KSTEPS; s++) {
    __syncthreads();                      // prior reads of bl done (also covers patch staging at s=0)
    {
      const uint4* src = (const uint4*)(WcombT + tid * KTOT + s * 32);
      uint4* dst = (uint4*)(bl + tid * 40);
      dst[0] = src[0]; dst[1] = src[1]; dst[2] = src[2]; dst[3] = src[3];
    }
    __syncthreads();
    int g  = s / 3;
    int c0 = (s - g * 3) * 32;
    int dy = g / 3, dx = g - dy * 3;
    short8 afr[4], bfr[4];
    #pragma unroll
    for (int mf = 0; mf < 4; mf++) {
      int p  = mf * 16 + lr;              // pixel in tile; A-frag m = lane&15
      int ty = p >> 5, tx = p & 31;
      afr[mf] = *(const short8*)(patch + ((ty + dy) * 34 + tx + dx) * 104 + c0 + quad * 8);
    }
    #pragma unroll
    for (int nf = 0; nf < 4; nf++) {
      int n = w * 64 + nf * 16 + lr;      // wave w owns gate w (n in [64w, 64w+64))
      bfr[nf] = *(const short8*)(bl + n * 40 + quad * 8);
    }
    #pragma unroll
    for (int mf = 0; mf < 4; mf++)
      #pragma unroll
      for (int nf = 0; nf < 4; nf++)
        acc[mf][nf] = __builtin_amdgcn_mfma_f32_16x16x32_bf16(afr[mf], bfr[nf], acc[mf][nf], 0, 0, 0);
  }

  __syncthreads();                         // last bl reads done
  {                                        // Wp -> LDS (region disjoint from gact)
    float4* d = (float4*)WpL;
    const float4* sWp = (const float4*)Wp;
    d[tid * 2]     = sWp[tid * 2];
    d[tid * 2 + 1] = sWp[tid * 2 + 1];
  }
  __syncthreads();

  // ---- residual (fp32, from global x) into regs: thread -> pixel mloc, cf [cb, cb+16)
  const int mloc = tid >> 2;
  const int cb   = (tid & 3) * 16;
  const int tyo  = mloc >> 5, txo = mloc & 31;
  const int gy   = y0 + tyo, gx = x0 + txo;
  float res[16];
  {
    float xv[32];
    const float4* xs = (const float4*)(x + ((((b * T_ + t) * H_ + gy) * W_ + gx) * CIN));
    #pragma unroll
    for (int j = 0; j < 8; j++) {
      float4 f = xs[j];
      xv[4 * j] = f.x; xv[4 * j + 1] = f.y; xv[4 * j + 2] = f.z; xv[4 * j + 3] = f.w;
    }
    #pragma unroll
    for (int j = 0; j < 16; j++) res[j] = bp[cb + j];
    for (int ci = 0; ci < 32; ci++) {
      float xf = xv[ci];
      #pragma unroll
      for (int j4 = 0; j4 < 4; j4++) {
        float4 wv = *(const float4*)(WpL + ci * 64 + cb + j4 * 4);
        res[j4 * 4 + 0] += xf * wv.x;
        res[j4 * 4 + 1] += xf * wv.y;
        res[j4 * 4 + 2] += xf * wv.z;
        res[j4 * 4 + 3] += xf * wv.w;
      }
    }
  }

  const int hbase   = ((b * H_ + gy) * W_ + gx) * F_ + cb;                 // h/c pixel base
  const int outbase = (((b * T_ + t) * H_ + gy) * W_ + gx) * F_ + cb;      // out + c_t location

  // ---- two-phase gate exchange (fp32) + LSTM cell combine
  #pragma unroll
  for (int p = 0; p < 2; p++) {
    #pragma unroll
    for (int mf = 0; mf < 4; mf++) {
      #pragma unroll
      for (int nh = 0; nh < 2; nh++) {
        int nf = p * 2 + nh;
        #pragma unroll
        for (int r = 0; r < 4; r++) {
          int mm = mf * 16 + quad * 4 + r;          // D row = quad*4 + reg
          float z = acc[mf][nf][r] + bias_r[nf];
          float a;
          if (w == 2) a = tanhf(z);                 // candidate gate
          else {                                    // hard_sigmoid for i, f, o
            a = __builtin_fmaf(z, 0.2f, 0.5f);
            a = fminf(fmaxf(a, 0.f), 1.f);
          }
          gact[(w * 64 + mm) * 33 + nh * 16 + lr] = a;
        }
      }
    }
    __syncthreads();
    if (((tid & 3) >> 1) == p) {                    // threads whose cf-half is this phase
      int cfp0 = cb - p * 32;                       // 0 or 16
      union { unsigned short hv[16]; uint4 q[2]; } hu;
      #pragma unroll
      for (int jj = 0; jj < 16; jj += 4) {
        // c_t lives at the SAME addresses this thread writes out to (read first!)
        float4 co = *(const float4*)(out + outbase + jj);
        float cold[4] = {co.x, co.y, co.z, co.w};
        float cn4[4], h4[4];
        #pragma unroll
        for (int e = 0; e < 4; e++) {
          int cfp = cfp0 + jj + e;
          float iv = gact[(0 * 64 + mloc) * 33 + cfp];
          float fv = gact[(1 * 64 + mloc) * 33 + cfp];
          float gv = gact[(2 * 64 + mloc) * 33 + cfp];
          float o_ = gact[(3 * 64 + mloc) * 33 + cfp];
          float cn = fv * cold[e] + iv * gv;
          float h  = o_ * tanhf(cn);
          cn4[e] = cn; h4[e] = h;
          hu.hv[jj + e] = f2bf(h);
        }
        if (t < T_ - 1)                             // c_{t+1} -> next slab (none needed after t=15)
          *(float4*)(out + outbase + TSLAB + jj) = make_float4(cn4[0], cn4[1], cn4[2], cn4[3]);
        *(float4*)(out + outbase + jj) = make_float4(h4[0] + res[jj + 0], h4[1] + res[jj + 1],
                                                     h4[2] + res[jj + 2], h4[3] + res[jj + 3]);
      }
      uint4* hd = (uint4*)(hnew + hbase);
      hd[0] = hu.q[0];
      hd[1] = hu.q[1];
    }
    __syncthreads();                                // gact reused (overwritten) next phase
  }
}

extern "C" void kernel_launch(void* const* d_in, const int* in_sizes, int n_in,
                              void* d_out, int out_size, void* d_ws, size_t ws_size,
                              hipStream_t stream) {
  const float* x    = (const float*)d_in[0];
  const float* Wx   = (const float*)d_in[1];
  const float* Wh   = (const float*)d_in[2];
  const float* bias = (const float*)d_in[3];
  const float* Wp   = (const float*)d_in[4];
  const float* bp   = (const float*)d_in[5];
  float* out = (float*)d_out;

  unsigned short* WcombT = (unsigned short*)d_ws;
  unsigned short* h0 = (unsigned short*)((char*)d_ws + OFF_H0);
  unsigned short* h1 = (unsigned short*)((char*)d_ws + OFF_H1);

  hipLaunchKernelGGL(prep_weights, dim3(864), dim3(256), 0, stream, Wx, Wh, WcombT);
  hipLaunchKernelGGL(prep_zero_h, dim3(1024), dim3(256), 0, stream,
                     (float4*)((char*)d_ws + OFF_H0));
  hipLaunchKernelGGL(prep_zero_c, dim3(1024), dim3(256), 0, stream, out);

  for (int t = 0; t < T_; t++) {
    const unsigned short* hp = (t & 1) ? h1 : h0;
    unsigned short*       hn = (t & 1) ? h0 : h1;
    hipLaunchKernelGGL(step_kernel, dim3(256), dim3(256), 0, stream,
                       x, bias, Wp, bp, WcombT, hp, hn, out, t);
  }
}

// Round 3
// 711.219 us; speedup vs baseline: 1.3466x; 1.3466x over previous
//
#include <hip/hip_runtime.h>

// ResidualConvLSTM2D on MI355X (gfx950).
// Fused per-timestep implicit GEMM: z = conv3x3([x_t || h_{t-1}], [Wx || Wh]) via
// bf16 MFMA (16x16x32), fp32 LSTM cell, fp32 residual 1x1 conv.
//
// R3: K-loop restructured for latency hiding:
//  - weights staged via __builtin_amdgcn_global_load_lds (width 16), from a
//    prep-built staging image WT[27][256][40] bf16 (pad rows included) so the
//    wave-uniform-base + lane*16 DMA layout matches the padded LDS tile.
//  - double-buffered weight tile, ONE barrier per K-step (prefetch s+1 during
//    compute of s); 54 -> 28 barriers.
//  - single-phase epilogue (full 256x64 gate tile in LDS), fast tanh.
//
// ws layout (4.53 MB; ws_size is ~8 MB — a 8.9 MB footprint corrupted the
// harness's pristine input copies in R1):
//   [0, 552960)          WT staged bf16 [27][256][40]
//   [557056, +2MB)       h ping  bf16 [4][64][64][64]
//   [2654208, +2MB)      h pong  bf16
// Cell state c (fp32) lives inside d_out: c_t at out[b][t][...] (read before
// that address is overwritten with the output), c_{t+1} into slab t+1.
#define B_ 4
#define T_ 16
#define H_ 64
#define W_ 64
#define CIN 32
#define F_ 64
#define NCH 256
#define KSTEPS 27
#define TSLAB (H_ * W_ * F_)   // 262144 floats between (b,t) and (b,t+1)

#define OFF_H0 557056
#define OFF_H1 2654208

typedef __attribute__((ext_vector_type(8))) short short8;
typedef __attribute__((ext_vector_type(4))) float floatx4;
typedef __attribute__((address_space(3))) unsigned int  lds_u32;
typedef __attribute__((address_space(1))) const unsigned int g_u32;

__device__ __forceinline__ unsigned short f2bf(float f) {
  union { float f; unsigned u; } v; v.f = f;
  unsigned r = v.u + 0x7FFFu + ((v.u >> 16) & 1u);   // round-to-nearest-even
  return (unsigned short)(r >> 16);
}

// tanh via hardware exp2: tanh(z) = 1 - 2/(exp(2z)+1). rcp approx (~1 ulp) is
// far inside the 4e-2 abs threshold. Saturates correctly for |z| large (inf/0).
__device__ __forceinline__ float tanh_fast(float z) {
  float e = __expf(2.0f * z);
  return 1.0f - 2.0f * __builtin_amdgcn_rcpf(e + 1.0f);
}

// Staging image: WT[s][n][c], c in [0,40); c<32 -> weight for k = s*32+c of
// output channel n (k = tap*96 + ch; ch<32 from Wx else Wh); c>=32 -> 0 (pad).
__global__ void prep_weights(const float* __restrict__ Wx, const float* __restrict__ Wh,
                             unsigned short* __restrict__ WT) {
  int idx = blockIdx.x * 256 + threadIdx.x;            // 0..276479
  int s = idx / 10240;
  int r = idx - s * 10240;
  int n = r / 40;
  int c = r - n * 40;
  unsigned short v = 0;
  if (c < 32) {
    int k  = s * 32 + c;
    int g  = k / 96;
    int ch = k - g * 96;
    float f = (ch < CIN) ? Wx[(g * CIN + ch) * NCH + n]
                         : Wh[(g * F_ + (ch - CIN)) * NCH + n];
    v = f2bf(f);
  }
  WT[idx] = v;
}

// Zero h ping+pong (4 MB in ws).
__global__ void prep_zero_h(float4* __restrict__ p) {
  int idx = blockIdx.x * 256 + threadIdx.x;
  p[idx] = make_float4(0.f, 0.f, 0.f, 0.f);
}

// Zero c0 = out slabs [b][0][...].
__global__ void prep_zero_c(float* __restrict__ out) {
  int idx = blockIdx.x * 256 + threadIdx.x;            // float4 units
  int b = idx >> 16;
  int i = idx & 65535;
  ((float4*)(out + (size_t)b * (T_ * TSLAB)))[i] = make_float4(0.f, 0.f, 0.f, 0.f);
}

// Issue 5x global_load_lds_dwordx4 staging one K-step's padded weight tile
// (256 rows x 80 B) for this wave's 64 rows. LDS dst must be wave-uniform.
__device__ __forceinline__ void stage_wt(const unsigned short* __restrict__ src,
                                         short* dstbuf, int w, int lane) {
  __attribute__((address_space(3))) unsigned short* d =
      (__attribute__((address_space(3))) unsigned short*)dstbuf + w * 2560;
  const unsigned short* s = src + w * 2560 + lane * 8;
  #pragma unroll
  for (int q = 0; q < 5; q++)
    __builtin_amdgcn_global_load_lds((g_u32*)(s + q * 512), (lds_u32*)(d + q * 512),
                                     16, 0, 0);
}

__global__ __launch_bounds__(256, 1)
void step_kernel(const float* __restrict__ x, const float* __restrict__ bias,
                 const float* __restrict__ Wp, const float* __restrict__ bp,
                 const unsigned short* __restrict__ WT,
                 const unsigned short* __restrict__ hprev,
                 unsigned short* __restrict__ hnew,
                 float* __restrict__ out, int t)
{
  // LDS: patch [4][34][104] sh (28288) | bl0 [256][40] sh (20480) | bl1 (20480)
  // epilogue reuse: gact [256][68] fp32 (69632 B) at 0, WpL 8 KB at 69632.
  __shared__ __align__(16) char smem[77824];
  short* patch = (short*)smem;
  short* bl0   = (short*)(smem + 28288);
  short* bl1   = (short*)(smem + 48768);
  float* gact  = (float*)smem;
  float* WpL   = (float*)(smem + 69632);

  const int tid  = threadIdx.x;
  const int w    = tid >> 6;
  const int lane = tid & 63;
  const int quad = lane >> 4;
  const int lr   = lane & 15;

  const int bid = blockIdx.x;
  const int b   = bid >> 6;
  const int rem = bid & 63;
  const int y0  = (rem >> 1) << 1;   // 2-row tile
  const int x0  = (rem & 1) << 5;    // 32-col half

  // ---- prefetch K-step 0 weights into bl0 (DMA, in flight during patch staging)
  stage_wt(WT, bl0, w, lane);

  // ---- stage input patch: 4 rows x 34 cols x 96 ch (x bf16 | h bf16)
  if (tid < 136) {
    int sy = tid / 34, sx = tid - sy * 34;
    int yy = y0 + sy - 1, xx = x0 + sx - 1;
    short* dst = patch + tid * 104;
    if (yy >= 0 && yy < H_ && xx >= 0 && xx < W_) {
      const float4* xs = (const float4*)(x + ((((b * T_ + t) * H_ + yy) * W_ + xx) * CIN));
      #pragma unroll
      for (int j = 0; j < 4; j++) {
        float4 f0 = xs[2 * j];
        float4 f1 = xs[2 * j + 1];
        union { short8 v; unsigned short u[8]; } pk;
        pk.u[0] = f2bf(f0.x); pk.u[1] = f2bf(f0.y); pk.u[2] = f2bf(f0.z); pk.u[3] = f2bf(f0.w);
        pk.u[4] = f2bf(f1.x); pk.u[5] = f2bf(f1.y); pk.u[6] = f2bf(f1.z); pk.u[7] = f2bf(f1.w);
        ((short8*)dst)[j] = pk.v;
      }
      const uint4* hs = (const uint4*)(hprev + ((b * H_ + yy) * W_ + xx) * F_);
      uint4* d2 = (uint4*)(dst + 32);
      #pragma unroll
      for (int j = 0; j < 8; j++) d2[j] = hs[j];
    } else {
      uint4 z = make_uint4(0, 0, 0, 0);
      uint4* d4 = (uint4*)dst;
      #pragma unroll
      for (int j = 0; j < 12; j++) d4[j] = z;
    }
  }

  float bias_r[4];
  #pragma unroll
  for (int nf = 0; nf < 4; nf++) bias_r[nf] = bias[w * 64 + nf * 16 + lr];

  floatx4 acc[4][4];
  #pragma unroll
  for (int mf = 0; mf < 4; mf++)
    #pragma unroll
    for (int nf = 0; nf < 4; nf++)
      acc[mf][nf] = (floatx4){0.f, 0.f, 0.f, 0.f};

  __syncthreads();   // patch staged + bl0 DMA drained (vmcnt(0) before barrier)

  // ---- K loop: 27 steps of BK=32 over K=864; double-buffered weight tile,
  //      ONE barrier per step; prefetch s+1 during compute of s.
  const unsigned short* wsrc = WT + 10240;   // staging image for s+1
  for (int s = 0; s < KSTEPS; s++) {
    short* cur = (s & 1) ? bl1 : bl0;
    if (s < KSTEPS - 1) {
      stage_wt(wsrc, (s & 1) ? bl0 : bl1, w, lane);
      wsrc += 10240;
    }
    int g  = s / 3;
    int c0 = (s - g * 3) * 32;
    int dy = g / 3, dx = g - dy * 3;
    short8 afr[4], bfr[4];
    #pragma unroll
    for (int mf = 0; mf < 4; mf++) {
      int p  = mf * 16 + lr;              // pixel in tile; A-frag m = lane&15
      int ty = p >> 5, tx = p & 31;
      afr[mf] = *(const short8*)(patch + ((ty + dy) * 34 + tx + dx) * 104 + c0 + quad * 8);
    }
    #pragma unroll
    for (int nf = 0; nf < 4; nf++) {
      int n = w * 64 + nf * 16 + lr;      // wave w owns gate w
      bfr[nf] = *(const short8*)(cur + n * 40 + quad * 8);
    }
    #pragma unroll
    for (int mf = 0; mf < 4; mf++)
      #pragma unroll
      for (int nf = 0; nf < 4; nf++)
        acc[mf][nf] = __builtin_amdgcn_mfma_f32_16x16x32_bf16(afr[mf], bfr[nf], acc[mf][nf], 0, 0, 0);
    __syncthreads();   // everyone done with cur; prefetch DMA drained for next iter
  }

  // ---- epilogue phase 1: activations -> gact[(gate*64+m)*68 + ch], WpL, prefetches
  #pragma unroll
  for (int mf = 0; mf < 4; mf++)
    #pragma unroll
    for (int nf = 0; nf < 4; nf++)
      #pragma unroll
      for (int r = 0; r < 4; r++) {
        int mm = mf * 16 + quad * 4 + r;          // D row = quad*4 + reg
        float z = acc[mf][nf][r] + bias_r[nf];
        float a;
        if (w == 2) a = tanh_fast(z);             // candidate gate
        else {                                    // hard_sigmoid for i, f, o
          a = __builtin_fmaf(z, 0.2f, 0.5f);
          a = fminf(fmaxf(a, 0.f), 1.f);
        }
        gact[(w * 64 + mm) * 68 + nf * 16 + lr] = a;
      }
  {                                               // Wp -> LDS
    float4* d = (float4*)WpL;
    const float4* sWp = (const float4*)Wp;
    d[tid * 2]     = sWp[tid * 2];
    d[tid * 2 + 1] = sWp[tid * 2 + 1];
  }

  const int mloc = tid >> 2;                      // pixel in tile
  const int cb   = (tid & 3) * 16;                // channel quarter
  const int tyo  = mloc >> 5, txo = mloc & 31;
  const int gy   = y0 + tyo, gx = x0 + txo;
  const int hbase   = ((b * H_ + gy) * W_ + gx) * F_ + cb;
  const int outbase = (((b * T_ + t) * H_ + gy) * W_ + gx) * F_ + cb;

  // prefetch x (residual) and c_t (global) before the barrier
  float xv[32];
  {
    const float4* xs = (const float4*)(x + ((((b * T_ + t) * H_ + gy) * W_ + gx) * CIN));
    #pragma unroll
    for (int j = 0; j < 8; j++) {
      float4 f = xs[j];
      xv[4 * j] = f.x; xv[4 * j + 1] = f.y; xv[4 * j + 2] = f.z; xv[4 * j + 3] = f.w;
    }
  }
  float4 co4[4];
  #pragma unroll
  for (int j = 0; j < 4; j++) co4[j] = *(const float4*)(out + outbase + 4 * j);

  __syncthreads();                                // gact + WpL visible

  // ---- residual 1x1 conv (fp32)
  float res[16];
  #pragma unroll
  for (int j = 0; j < 16; j++) res[j] = bp[cb + j];
  for (int ci = 0; ci < 32; ci++) {
    float xf = xv[ci];
    #pragma unroll
    for (int j4 = 0; j4 < 4; j4++) {
      float4 wv = *(const float4*)(WpL + ci * 64 + cb + j4 * 4);
      res[j4 * 4 + 0] += xf * wv.x;
      res[j4 * 4 + 1] += xf * wv.y;
      res[j4 * 4 + 2] += xf * wv.z;
      res[j4 * 4 + 3] += xf * wv.w;
    }
  }

  // ---- LSTM cell combine (single phase, all threads)
  union { unsigned short hv[16]; uint4 q[2]; } hu;
  #pragma unroll
  for (int j4 = 0; j4 < 4; j4++) {
    int jj = j4 * 4;
    float4 gi = *(const float4*)(gact + (0 * 64 + mloc) * 68 + cb + jj);
    float4 gf = *(const float4*)(gact + (1 * 64 + mloc) * 68 + cb + jj);
    float4 gg = *(const float4*)(gact + (2 * 64 + mloc) * 68 + cb + jj);
    float4 go = *(const float4*)(gact + (3 * 64 + mloc) * 68 + cb + jj);
    float cold[4] = {co4[j4].x, co4[j4].y, co4[j4].z, co4[j4].w};
    float iv[4] = {gi.x, gi.y, gi.z, gi.w};
    float fv[4] = {gf.x, gf.y, gf.z, gf.w};
    float gv[4] = {gg.x, gg.y, gg.z, gg.w};
    float ov[4] = {go.x, go.y, go.z, go.w};
    float cn4[4], h4[4];
    #pragma unroll
    for (int e = 0; e < 4; e++) {
      float cn = fv[e] * cold[e] + iv[e] * gv[e];
      float h  = ov[e] * tanh_fast(cn);
      cn4[e] = cn; h4[e] = h;
      hu.hv[jj + e] = f2bf(h);
    }
    if (t < T_ - 1)                               // c_{t+1} -> next out slab
      *(float4*)(out + outbase + TSLAB + jj) = make_float4(cn4[0], cn4[1], cn4[2], cn4[3]);
    *(float4*)(out + outbase + jj) = make_float4(h4[0] + res[jj + 0], h4[1] + res[jj + 1],
                                                 h4[2] + res[jj + 2], h4[3] + res[jj + 3]);
  }
  uint4* hd = (uint4*)(hnew + hbase);
  hd[0] = hu.q[0];
  hd[1] = hu.q[1];
}

extern "C" void kernel_launch(void* const* d_in, const int* in_sizes, int n_in,
                              void* d_out, int out_size, void* d_ws, size_t ws_size,
                              hipStream_t stream) {
  const float* x    = (const float*)d_in[0];
  const float* Wx   = (const float*)d_in[1];
  const float* Wh   = (const float*)d_in[2];
  const float* bias = (const float*)d_in[3];
  const float* Wp   = (const float*)d_in[4];
  const float* bp   = (const float*)d_in[5];
  float* out = (float*)d_out;

  unsigned short* WT = (unsigned short*)d_ws;
  unsigned short* h0 = (unsigned short*)((char*)d_ws + OFF_H0);
  unsigned short* h1 = (unsigned short*)((char*)d_ws + OFF_H1);

  hipLaunchKernelGGL(prep_weights, dim3(1080), dim3(256), 0, stream, Wx, Wh, WT);
  hipLaunchKernelGGL(prep_zero_h, dim3(1024), dim3(256), 0, stream,
                     (float4*)((char*)d_ws + OFF_H0));
  hipLaunchKernelGGL(prep_zero_c, dim3(1024), dim3(256), 0, stream, out);

  for (int t = 0; t < T_; t++) {
    const unsigned short* hp = (t & 1) ? h1 : h0;
    unsigned short*       hn = (t & 1) ? h0 : h1;
    hipLaunchKernelGGL(step_kernel, dim3(256), dim3(256), 0, stream,
                       x, bias, Wp, bp, WT, hp, hn, out, t);
  }
}